// Round 8
// baseline (1119.450 us; speedup 1.0000x reference)
//
#include <hip/hip_runtime.h>

typedef unsigned short ushort_t;
typedef unsigned int uint_t;

#define NN 20000
#define EE 320000
#define CC 32
#define NEL 10
#define GG 64
#define TTT 1000
#define NBB 8
#define HIDD 64
#define NPB 4           // nodes per block in k_fused (NN = 5000*4)
#define MAXDEG 64       // safety clamp (deg ~ Poisson(16); P(>64) ~ 1e-19)

typedef __attribute__((ext_vector_type(8))) short bf16x8;
typedef __attribute__((ext_vector_type(4))) float f32x4;

__device__ __forceinline__ float bits2f(uint_t b) { union { uint_t u; float f; } v; v.u = b; return v.f; }
__device__ __forceinline__ ushort_t f2b(float f) {
  union { float f; uint_t u; } v; v.f = f;
  uint_t r = (v.u + 0x7fffu + ((v.u >> 16) & 1u)) >> 16;
  return (ushort_t)r;
}
__device__ __forceinline__ uint_t pk(float a, float b) {
  return (uint_t)f2b(a) | ((uint_t)f2b(b) << 16);
}
__device__ __forceinline__ float lo16(uint_t u) { return bits2f(u << 16); }
__device__ __forceinline__ float hi16(uint_t u) { return bits2f(u & 0xffff0000u); }
__device__ __forceinline__ float b2f(ushort_t u) { return bits2f(((uint_t)u) << 16); }

// ---------------- K1: node prep (also zeroes deg) ----------------
__global__ __launch_bounds__(256) void k_prep(
    const float* __restrict__ positions, const float* __restrict__ node_attrs,
    const float* __restrict__ eps, const float* __restrict__ alpha_bar,
    const float* __restrict__ W_embed, const float* __restrict__ W_sc,
    const int* __restrict__ batch, const int* __restrict__ tarr,
    float* __restrict__ pos_noisy, float* __restrict__ scalA,
    float* __restrict__ sc_skip, float* __restrict__ pred, int* __restrict__ deg)
{
  int n = blockIdx.x * 256 + threadIdx.x;
  if (n >= NN) return;
  deg[n] = 0;
  int g = batch[n];
  int tn = tarr[g];
  float ab = alpha_bar[tn];
  float sa = sqrtf(ab), sb = sqrtf(fmaxf(1.0f - ab, 0.0f));
#pragma unroll
  for (int j = 0; j < 3; ++j)
    pos_noisy[n * 3 + j] = sa * positions[n * 3 + j] + sb * eps[n * 13 + 10 + j];
  float an[10];
#pragma unroll
  for (int j = 0; j < 10; ++j)
    an[j] = sa * 0.25f * node_attrs[n * 10 + j] + sb * eps[n * 13 + j];
  float tf = (float)tn * (1.0f / (float)TTT);
  for (int d = 0; d < CC; ++d) {
    float h = tf * W_embed[10 * CC + d];
    float sk = 0.0f;
#pragma unroll
    for (int j = 0; j < 10; ++j) {
      h = fmaf(an[j], W_embed[j * CC + d], h);
      sk = fmaf(an[j], W_sc[j * CC + d], sk);
    }
    scalA[n * CC + d] = h;
    sc_skip[n * CC + d] = sk;
  }
#pragma unroll
  for (int j = 0; j < 13; ++j) pred[n * 13 + j] = 0.0f;
}

// ---------------- K2a: receiver histogram ----------------
__global__ __launch_bounds__(256) void k_edge_deg(const int* __restrict__ ei,
    int* __restrict__ deg)
{
  int e = blockIdx.x * 256 + threadIdx.x;  // EE = 1250*256 exactly
  atomicAdd(&deg[ei[EE + e]], 1);
}

// ---------------- K3: exclusive scan deg -> offs, cursor; zero loss accum ----
__global__ __launch_bounds__(1024) void k_scan(const int* __restrict__ deg,
    int* __restrict__ offs, int* __restrict__ cursor,
    float* __restrict__ lnum, float* __restrict__ lcnt)
{
  __shared__ int wsums[16];
  __shared__ int woffs[16];
  int tid = threadIdx.x, lane = tid & 63, wv = tid >> 6;
  if (tid < GG) { lnum[tid] = 0.0f; lcnt[tid] = 0.0f; }
  int base = tid * 20;
  int loc[20];
  int s = 0;
#pragma unroll
  for (int j = 0; j < 20; ++j) {
    int idx = base + j;
    int v = (idx < NN) ? deg[idx] : 0;
    loc[j] = s; s += v;
  }
  int inc = s;
  for (int o = 1; o < 64; o <<= 1) {
    int v = __shfl_up(inc, o, 64);
    if (lane >= o) inc += v;
  }
  if (lane == 63) wsums[wv] = inc;
  __syncthreads();
  if (wv == 0 && lane < 16) {
    int v = wsums[lane];
    int i2 = v;
    for (int o = 1; o < 16; o <<= 1) {
      int vv = __shfl_up(i2, o, 16);
      if (lane >= o) i2 += vv;
    }
    woffs[lane] = i2 - v;
  }
  __syncthreads();
  int texcl = woffs[wv] + (inc - s);
#pragma unroll
  for (int j = 0; j < 20; ++j) {
    int idx = base + j;
    if (idx < NN) { int v = texcl + loc[j]; offs[idx] = v; cursor[idx] = v; }
  }
  if (tid == 1023) offs[NN] = EE;
}

// ---------------- K4: edge geometry, written into receiver-sorted slots ------
__global__ __launch_bounds__(256) void k_edge2(
    const float* __restrict__ pos_noisy, const float* __restrict__ shifts,
    const int* __restrict__ ei, int* __restrict__ cursor,
    ushort_t* __restrict__ Ys, ushort_t* __restrict__ efs, int* __restrict__ snds)
{
  int e = blockIdx.x * 256 + threadIdx.x;  // EE exact
  int snd = ei[e], rcv = ei[EE + e];
  float vx = pos_noisy[rcv * 3 + 0] - pos_noisy[snd * 3 + 0] + shifts[e * 3 + 0];
  float vy = pos_noisy[rcv * 3 + 1] - pos_noisy[snd * 3 + 1] + shifts[e * 3 + 1];
  float vz = pos_noisy[rcv * 3 + 2] - pos_noisy[snd * 3 + 2] + shifts[e * 3 + 2];
  float r2 = vx * vx + vy * vy + vz * vz + 1e-12f;
  float r = sqrtf(r2);
  float inv = 1.0f / r;
  float x = vx * inv, y = vy * inv, z = vz * inv;

  const float s3 = 1.7320508075688772f, s15 = 3.872983346207417f, s5 = 2.23606797749979f;
  const float s105 = 10.246950765959598f, s7 = 2.6457513110645907f;
  const float s35_8 = 2.091650066335189f, s21_8 = 1.6201851746019651f;
  float yv[16];
  yv[0] = 1.0f;
  yv[1] = s3 * x; yv[2] = s3 * y; yv[3] = s3 * z;
  yv[4] = s15 * x * y;
  yv[5] = s15 * y * z;
  yv[6] = 0.5f * s5 * (3.0f * z * z - 1.0f);
  yv[7] = s15 * x * z;
  yv[8] = 0.5f * s15 * (x * x - y * y);
  yv[9] = s35_8 * y * (3.0f * x * x - y * y);
  yv[10] = s105 * x * y * z;
  yv[11] = s21_8 * y * (5.0f * z * z - 1.0f);
  yv[12] = 0.5f * s7 * (5.0f * z * z * z - 3.0f * z);
  yv[13] = s21_8 * x * (5.0f * z * z - 1.0f);
  yv[14] = 0.5f * s105 * z * (x * x - y * y);
  yv[15] = s35_8 * x * (x * x - 3.0f * y * y);

  // radial embed: sqrt(2/5) * sin(n*pi*rc/5)/rc * poly_cutoff(r/5)
  float rc = fmaxf(r, 1e-9f);
  float pref = 0.6324555320336759f / rc;
  float th = 0.6283185307179586f * rc;
  float s1 = __sinf(th), c1 = __cosf(th);
  float xr = r * 0.2f;
  float fcut = 0.0f;
  if (xr < 1.0f) {
    float x2 = xr * xr, x3 = x2 * xr;
    float x6 = x3 * x3, x7 = x6 * xr, x8 = x7 * xr;
    fcut = 1.0f - 28.0f * x6 + 48.0f * x7 - 21.0f * x8;
  }
  float efv[8];
  float sp = 0.0f, scur = s1, c2 = 2.0f * c1;
#pragma unroll
  for (int b = 0; b < 8; ++b) {
    efv[b] = pref * scur * fcut;
    float nx = c2 * scur - sp;   // sin((n+1)th) = 2cos(th)sin(n th) - sin((n-1)th)
    sp = scur; scur = nx;
  }

  int slot = atomicAdd(&cursor[rcv], 1);
  snds[slot] = snd;
  uint4* Y4 = (uint4*)Ys;
  Y4[(size_t)slot * 2 + 0] = make_uint4(pk(yv[0], yv[1]), pk(yv[2], yv[3]),
                                        pk(yv[4], yv[5]), pk(yv[6], yv[7]));
  Y4[(size_t)slot * 2 + 1] = make_uint4(pk(yv[8], yv[9]), pk(yv[10], yv[11]),
                                        pk(yv[12], yv[13]), pk(yv[14], yv[15]));
  ((uint4*)efs)[slot] = make_uint4(pk(efv[0], efv[1]), pk(efv[2], efv[3]),
                                   pk(efv[4], efv[5]), pk(efv[6], efv[7]));
}

// ---------------- K5: fully fused layer -------------------------------------
// Block owns NPB=4 complete nodes (all their sorted edges). Per 16-edge tile:
// h1 in registers -> MFMA vs LDS W2^T -> *ss (L2 gather) -> *Y (LDS) ->
// shfl-reduce over edges -> LDS atomic agg -> mix/poly/readout. No global rw.
__global__ __launch_bounds__(256) void k_fused(
    const ushort_t* __restrict__ efs, const ushort_t* __restrict__ Ys,
    const int* __restrict__ snds, const int* __restrict__ offs,
    const float* __restrict__ W_r1, const float* __restrict__ W_r2,
    const float* __restrict__ scal_in, float* __restrict__ scal_out,
    const float* __restrict__ W_mix, const float* __restrict__ W_prod,
    const float* __restrict__ W_ro_s, const float* __restrict__ W_ro_v,
    const float* __restrict__ sc_skip, float* __restrict__ pred, int layer)
{
  __shared__ __align__(16) ushort_t w2t[128][72];   // W2^T bf16, 16B-aligned rows (18.4 KB)
  __shared__ __align__(16) ushort_t ysh[256][16];   // Y bf16 per padded slot (8.2 KB)
  __shared__ float agg[NPB][CC][20];                // lm-padded (10.2 KB)
  __shared__ float lf[NPB][CC][4];                  // (2 KB)

  int tid = threadIdx.x;
  int n0 = blockIdx.x * NPB;
  const float* W1g = W_r1 + layer * NBB * HIDD;
  const float* W2g = W_r2 + layer * HIDD * 128;

  // per-node degrees + tile prefix (all threads, cheap & uniform)
  int o0 = offs[n0], o1 = offs[n0 + 1], o2 = offs[n0 + 2], o3 = offs[n0 + 3], o4 = offs[n0 + 4];
  int d0 = min(o1 - o0, MAXDEG), d1 = min(o2 - o1, MAXDEG);
  int d2 = min(o3 - o2, MAXDEG), d3 = min(o4 - o3, MAXDEG);
  int p1 = (d0 + 15) >> 4;
  int p2 = p1 + ((d1 + 15) >> 4);
  int p3 = p2 + ((d2 + 15) >> 4);
  int T  = p3 + ((d3 + 15) >> 4);   // <= 16 tiles

  // zero agg
  for (int i = tid; i < NPB * CC * 20; i += 256) ((float*)agg)[i] = 0.0f;
  // stage W2^T (bf16)
  for (int idx = tid; idx < HIDD * 128; idx += 256) {
    int k = idx >> 7, n = idx & 127;
    w2t[n][k] = f2b(W2g[idx]);
  }
  // stage Y per padded slot (zeros for pad slots)
  if (tid < T * 16) {
    int t = tid >> 4, r = tid & 15;
    int j = (t < p1) ? 0 : (t < p2) ? 1 : (t < p3) ? 2 : 3;
    int oj = (j == 0) ? o0 : (j == 1) ? o1 : (j == 2) ? o2 : o3;
    int pj = (j == 0) ? 0 : (j == 1) ? p1 : (j == 2) ? p2 : p3;
    int dj = (j == 0) ? d0 : (j == 1) ? d1 : (j == 2) ? d2 : d3;
    int k = (t - pj) * 16 + r;
    uint4 a = make_uint4(0, 0, 0, 0), b = make_uint4(0, 0, 0, 0);
    if (k < dj) {
      const uint4* Y4 = (const uint4*)Ys;
      size_t ge = (size_t)(oj + k);
      a = Y4[ge * 2]; b = Y4[ge * 2 + 1];
    }
    *(uint4*)&ysh[tid][0] = a;
    *(uint4*)&ysh[tid][8] = b;
  }
  __syncthreads();

  int w = tid >> 6, lane = tid & 63;
  int c = lane & 15, quad = lane >> 4;
  int l = c & 3, nlm = 2 * l + 1, lmb = l * l;   // L_OF_LM groups: lm = l*l .. l*l+2l

  for (int t = w; t < T; t += 4) {
    int j = (t < p1) ? 0 : (t < p2) ? 1 : (t < p3) ? 2 : 3;
    int oj = (j == 0) ? o0 : (j == 1) ? o1 : (j == 2) ? o2 : o3;
    int pj = (j == 0) ? 0 : (j == 1) ? p1 : (j == 2) ? p2 : p3;
    int dj = (j == 0) ? d0 : (j == 1) ? d1 : (j == 2) ? d2 : d3;
    int kbase = (t - pj) * 16;

    // ---- A-fragments: this lane computes the 16 h-values it feeds to MFMA
    // for edge (kbase + c): h[quad*8+jj] and h[32+quad*8+jj]
    bf16x8 a0, a1;
    {
      int kc = kbase + c;
      float ef8[8] = {0, 0, 0, 0, 0, 0, 0, 0};
      if (kc < dj) {
        uint4 q = ((const uint4*)efs)[(size_t)(oj + kc)];
        ef8[0] = lo16(q.x); ef8[1] = hi16(q.x); ef8[2] = lo16(q.y); ef8[3] = hi16(q.y);
        ef8[4] = lo16(q.z); ef8[5] = hi16(q.z); ef8[6] = lo16(q.w); ef8[7] = hi16(q.w);
      }
      float h0[8] = {0, 0, 0, 0, 0, 0, 0, 0};
      float h1v[8] = {0, 0, 0, 0, 0, 0, 0, 0};
#pragma unroll
      for (int b = 0; b < 8; ++b) {
        const float* Wb = W1g + b * HIDD;
        float4 wa = *(const float4*)&Wb[quad * 8];
        float4 wbv = *(const float4*)&Wb[quad * 8 + 4];
        float4 wc = *(const float4*)&Wb[32 + quad * 8];
        float4 wd = *(const float4*)&Wb[32 + quad * 8 + 4];
        float e = ef8[b];
        h0[0] = fmaf(e, wa.x, h0[0]); h0[1] = fmaf(e, wa.y, h0[1]);
        h0[2] = fmaf(e, wa.z, h0[2]); h0[3] = fmaf(e, wa.w, h0[3]);
        h0[4] = fmaf(e, wbv.x, h0[4]); h0[5] = fmaf(e, wbv.y, h0[5]);
        h0[6] = fmaf(e, wbv.z, h0[6]); h0[7] = fmaf(e, wbv.w, h0[7]);
        h1v[0] = fmaf(e, wc.x, h1v[0]); h1v[1] = fmaf(e, wc.y, h1v[1]);
        h1v[2] = fmaf(e, wc.z, h1v[2]); h1v[3] = fmaf(e, wc.w, h1v[3]);
        h1v[4] = fmaf(e, wd.x, h1v[4]); h1v[5] = fmaf(e, wd.y, h1v[5]);
        h1v[6] = fmaf(e, wd.z, h1v[6]); h1v[7] = fmaf(e, wd.w, h1v[7]);
      }
#pragma unroll
      for (int jj = 0; jj < 8; ++jj) {
        float v0 = h0[jj];  v0 = v0 / (1.0f + __expf(-v0));
        float v1 = h1v[jj]; v1 = v1 / (1.0f + __expf(-v1));
        a0[jj] = (short)f2b(v0);
        a1[jj] = (short)f2b(v1);
      }
    }

    // ---- epilogue preload: senders + Y for this lane's 4 edge-rows
    int snd_[4];
#pragma unroll
    for (int r = 0; r < 4; ++r) {
      int kr = kbase + quad * 4 + r;
      int ger = oj + ((kr < dj) ? kr : 0);   // dummy (valid mem) for pad rows
      snd_[r] = snds[ger];
    }
    float yv_[4][7];
#pragma unroll
    for (int r = 0; r < 4; ++r) {
      int slot = t * 16 + quad * 4 + r;      // pad rows: ysh zeroed -> contributes 0
#pragma unroll
      for (int i = 0; i < 7; ++i)
        if (i < nlm) yv_[r][i] = b2f(ysh[slot][lmb + i]);
    }

    // ---- 8 n-tiles: MFMA + scale + reduce-over-edges + LDS atomic
#pragma unroll
    for (int nt = 0; nt < 8; ++nt) {
      bf16x8 b0 = *(const bf16x8*)&w2t[nt * 16 + c][quad * 8];
      bf16x8 b1 = *(const bf16x8*)&w2t[nt * 16 + c][32 + quad * 8];
      f32x4 acc = {0.0f, 0.0f, 0.0f, 0.0f};
      acc = __builtin_amdgcn_mfma_f32_16x16x32_bf16(a0, b0, acc, 0, 0, 0);
      acc = __builtin_amdgcn_mfma_f32_16x16x32_bf16(a1, b1, acc, 0, 0, 0);
      int cc = 4 * nt + (c >> 2);
      float v[7];
#pragma unroll
      for (int i = 0; i < 7; ++i) v[i] = 0.0f;
#pragma unroll
      for (int r = 0; r < 4; ++r) {
        float val = acc[r] * scal_in[(size_t)snd_[r] * CC + cc];
#pragma unroll
        for (int i = 0; i < 7; ++i)
          if (i < nlm) v[i] = fmaf(val, yv_[r][i], v[i]);
      }
#pragma unroll
      for (int i = 0; i < 7; ++i) {
        if (i < nlm) {                      // partners lane^16/32/48 share c -> same mask
          float s2 = v[i];
          s2 += __shfl_xor(s2, 16, 64);
          s2 += __shfl_xor(s2, 32, 64);
          if (quad == 0) atomicAdd(&agg[j][cc][lmb + i], s2);
        }
      }
    }
  }
  __syncthreads();

  // ---- mix + poly + skip + scal_out + lf (wave w -> node n0+w)
  {
    int d = lane >> 1;
    int kh = lane & 1, kb = kh * 8;
    int n = n0 + w;
    float ft[8] = {0, 0, 0, 0, 0, 0, 0, 0};
    const float* Wm = W_mix + layer * 4096;
    for (int cc2 = 0; cc2 < CC; ++cc2) {
      float la[8];
      *(float4*)&la[0] = *(const float4*)&agg[w][cc2][kb];
      *(float4*)&la[4] = *(const float4*)&agg[w][cc2][kb + 4];
      float m0 = Wm[cc2 * CC + d];
      float m1 = Wm[1024 + cc2 * CC + d];
      float m2 = Wm[2048 + cc2 * CC + d];
      float m3 = Wm[3072 + cc2 * CC + d];
      float u0 = kh ? m2 : m0;
      float u13 = kh ? m3 : m1;
      float u47 = kh ? m3 : m2;
      ft[0] = fmaf(la[0], u0, ft[0]);
      ft[1] = fmaf(la[1], u13, ft[1]);
      ft[2] = fmaf(la[2], u13, ft[2]);
      ft[3] = fmaf(la[3], u13, ft[3]);
      ft[4] = fmaf(la[4], u47, ft[4]);
      ft[5] = fmaf(la[5], u47, ft[5]);
      ft[6] = fmaf(la[6], u47, ft[6]);
      ft[7] = fmaf(la[7], u47, ft[7]);
    }
#pragma unroll
    for (int i = 0; i < 8; ++i) ft[i] *= (1.0f / 16.0f);   // / AVG_NEIGH
    float sv = __shfl(ft[0], lane & 62, 64);   // k=0 pre-poly from even lane of pair
    const float* Wp = W_prod + layer * 96;
    float p0 = Wp[d], p1v = Wp[32 + d], p2v = Wp[64 + d];
    float poly = fmaf(fmaf(p2v, sv, p1v), sv, p0);
#pragma unroll
    for (int i = 0; i < 8; ++i) ft[i] *= poly;
    if (layer == 0 && kh == 0) ft[0] += sc_skip[n * CC + d];
    if (kh == 0) {
      scal_out[n * CC + d] = ft[0];
      lf[w][d][0] = ft[0]; lf[w][d][1] = ft[1]; lf[w][d][2] = ft[2]; lf[w][d][3] = ft[3];
    }
  }
  __syncthreads();

  // ---- readout
  if (lane < 13) {
    int n = n0 + w;
    float sum = 0.0f;
    if (lane < 10) {
      const float* Wr = W_ro_s + layer * CC * NEL;
      for (int dd = 0; dd < CC; ++dd) sum = fmaf(lf[w][dd][0], Wr[dd * NEL + lane], sum);
    } else {
      int mm = lane - 10;
      const float* Wv = W_ro_v + layer * CC;
      for (int dd = 0; dd < CC; ++dd) sum = fmaf(lf[w][dd][1 + mm], Wv[dd], sum);
    }
    pred[n * 13 + lane] += sum;
  }
}

// ---------------- K7: loss accumulation (hierarchical: LDS -> global) --------
__global__ __launch_bounds__(256) void k_loss(const float* __restrict__ pred,
    const float* __restrict__ eps, const int* __restrict__ batch,
    float* __restrict__ lnum, float* __restrict__ lcnt)
{
  __shared__ float psum[GG];
  __shared__ int pcnt[GG];
  int tid = threadIdx.x;
  if (tid < GG) { psum[tid] = 0.0f; pcnt[tid] = 0; }
  __syncthreads();
  int n = blockIdx.x * 256 + tid;
  if (n < NN) {
    int g = batch[n];
    float sum = 0.0f;
#pragma unroll
    for (int j = 0; j < 13; ++j) {
      float dlt = pred[n * 13 + j] - eps[n * 13 + j];
      sum = fmaf(dlt, dlt, sum);
    }
    atomicAdd(&psum[g], sum);
    atomicAdd(&pcnt[g], 1);
  }
  __syncthreads();
  if (tid < GG && pcnt[tid] > 0) {
    atomicAdd(&lnum[tid], psum[tid]);
    atomicAdd(&lcnt[tid], (float)pcnt[tid]);
  }
}

__global__ void k_final(const float* __restrict__ lnum, const float* __restrict__ lcnt,
    float* __restrict__ out)
{
  int g = threadIdx.x;
  if (g < GG) {
    float nn = fmaxf(lcnt[g], 1.0f);
    out[g] = 0.5f * lnum[g] / (nn * 13.0f);
  }
}

extern "C" void kernel_launch(void* const* d_in, const int* in_sizes, int n_in,
                              void* d_out, int out_size, void* d_ws, size_t ws_size,
                              hipStream_t stream) {
  const float* positions  = (const float*)d_in[0];
  const float* node_attrs = (const float*)d_in[1];
  const float* shifts     = (const float*)d_in[2];
  const float* eps        = (const float*)d_in[3];
  const float* alpha_bar  = (const float*)d_in[4];
  const float* W_embed    = (const float*)d_in[5];
  const float* W_r1       = (const float*)d_in[6];
  const float* W_r2       = (const float*)d_in[7];
  const float* W_mix      = (const float*)d_in[8];
  const float* W_sc       = (const float*)d_in[9];
  const float* W_prod     = (const float*)d_in[10];
  const float* W_ro_s     = (const float*)d_in[11];
  const float* W_ro_v     = (const float*)d_in[12];
  const int* edge_index   = (const int*)d_in[13];
  const int* batch        = (const int*)d_in[14];
  const int* tarr         = (const int*)d_in[15];
  float* out = (float*)d_out;

  char* ws = (char*)d_ws;
  size_t off = 0;
  auto alloc = [&](size_t bytes) -> void* {
    void* p = ws + off;
    off = (off + bytes + 255) & ~(size_t)255;
    return p;
  };
  // total ~25 MB (no rw intermediate anymore)
  float* pos_noisy = (float*)alloc(NN * 3 * 4);
  float* scalA     = (float*)alloc(NN * CC * 4);
  float* scalB     = (float*)alloc(NN * CC * 4);
  float* sc_skip   = (float*)alloc(NN * CC * 4);
  float* pred      = (float*)alloc(NN * 13 * 4);
  ushort_t* Ys     = (ushort_t*)alloc((size_t)EE * 16 * 2);  // sorted, bf16
  ushort_t* efs    = (ushort_t*)alloc((size_t)EE * 8 * 2);   // sorted, bf16
  int* snds        = (int*)alloc((size_t)EE * 4);            // sorted sender ids
  int* deg         = (int*)alloc(NN * 4);
  int* offs        = (int*)alloc((NN + 1) * 4);
  int* cursor      = (int*)alloc(NN * 4);
  float* lnum      = (float*)alloc(GG * 4);
  float* lcnt      = (float*)alloc(GG * 4);
  (void)ws_size; (void)in_sizes; (void)n_in; (void)out_size;

  const int NB_N = (NN + 255) / 256;   // 79
  const int NB_E = EE / 256;           // 1250

  k_prep<<<NB_N, 256, 0, stream>>>(positions, node_attrs, eps, alpha_bar, W_embed,
                                   W_sc, batch, tarr, pos_noisy, scalA, sc_skip, pred, deg);
  k_edge_deg<<<NB_E, 256, 0, stream>>>(edge_index, deg);
  k_scan<<<1, 1024, 0, stream>>>(deg, offs, cursor, lnum, lcnt);
  k_edge2<<<NB_E, 256, 0, stream>>>(pos_noisy, shifts, edge_index, cursor, Ys, efs, snds);

  for (int layer = 0; layer < 2; ++layer) {
    const float* sin_p = (layer == 0) ? scalA : scalB;
    float* sout_p      = (layer == 0) ? scalB : scalA;
    k_fused<<<NN / NPB, 256, 0, stream>>>(efs, Ys, snds, offs, W_r1, W_r2,
                                          sin_p, sout_p, W_mix, W_prod,
                                          W_ro_s, W_ro_v, sc_skip, pred, layer);
  }

  k_loss<<<NB_N, 256, 0, stream>>>(pred, eps, batch, lnum, lcnt);
  k_final<<<1, 64, 0, stream>>>(lnum, lcnt, out);
}

// Round 9
// 366.892 us; speedup vs baseline: 3.0512x; 3.0512x over previous
//
#include <hip/hip_runtime.h>

typedef unsigned short ushort_t;
typedef unsigned int uint_t;

#define NN 20000
#define EE 320000
#define CC 32
#define NEL 10
#define GG 64
#define TTT 1000
#define NBB 8
#define HIDD 64
#define NPB 4           // nodes per block in k_flay (NN = 5000*4)
#define MAXDEG 64       // safety clamp (deg ~ Poisson(16); P(>64) ~ 1e-19)

typedef __attribute__((ext_vector_type(8))) short bf16x8;
typedef __attribute__((ext_vector_type(4))) float f32x4;

__device__ __forceinline__ float bits2f(uint_t b) { union { uint_t u; float f; } v; v.u = b; return v.f; }
__device__ __forceinline__ ushort_t f2b(float f) {
  union { float f; uint_t u; } v; v.f = f;
  uint_t r = (v.u + 0x7fffu + ((v.u >> 16) & 1u)) >> 16;
  return (ushort_t)r;
}
__device__ __forceinline__ uint_t pk(float a, float b) {
  return (uint_t)f2b(a) | ((uint_t)f2b(b) << 16);
}
__device__ __forceinline__ float lo16(uint_t u) { return bits2f(u << 16); }
__device__ __forceinline__ float hi16(uint_t u) { return bits2f(u & 0xffff0000u); }

// ---------------- K1: node prep (also zeroes deg) ----------------
__global__ __launch_bounds__(256) void k_prep(
    const float* __restrict__ positions, const float* __restrict__ node_attrs,
    const float* __restrict__ eps, const float* __restrict__ alpha_bar,
    const float* __restrict__ W_embed, const float* __restrict__ W_sc,
    const int* __restrict__ batch, const int* __restrict__ tarr,
    float* __restrict__ pos_noisy, float* __restrict__ scalA,
    float* __restrict__ sc_skip, float* __restrict__ pred, int* __restrict__ deg)
{
  int n = blockIdx.x * 256 + threadIdx.x;
  if (n >= NN) return;
  deg[n] = 0;
  int g = batch[n];
  int tn = tarr[g];
  float ab = alpha_bar[tn];
  float sa = sqrtf(ab), sb = sqrtf(fmaxf(1.0f - ab, 0.0f));
#pragma unroll
  for (int j = 0; j < 3; ++j)
    pos_noisy[n * 3 + j] = sa * positions[n * 3 + j] + sb * eps[n * 13 + 10 + j];
  float an[10];
#pragma unroll
  for (int j = 0; j < 10; ++j)
    an[j] = sa * 0.25f * node_attrs[n * 10 + j] + sb * eps[n * 13 + j];
  float tf = (float)tn * (1.0f / (float)TTT);
  for (int d = 0; d < CC; ++d) {
    float h = tf * W_embed[10 * CC + d];
    float sk = 0.0f;
#pragma unroll
    for (int j = 0; j < 10; ++j) {
      h = fmaf(an[j], W_embed[j * CC + d], h);
      sk = fmaf(an[j], W_sc[j * CC + d], sk);
    }
    scalA[n * CC + d] = h;
    sc_skip[n * CC + d] = sk;
  }
#pragma unroll
  for (int j = 0; j < 13; ++j) pred[n * 13 + j] = 0.0f;
}

// ---------------- K2a: receiver histogram ----------------
__global__ __launch_bounds__(256) void k_edge_deg(const int* __restrict__ ei,
    int* __restrict__ deg)
{
  int e = blockIdx.x * 256 + threadIdx.x;  // EE = 1250*256 exactly
  atomicAdd(&deg[ei[EE + e]], 1);
}

// ---------------- K3: exclusive scan deg -> offs, cursor; zero accumulators --
__global__ __launch_bounds__(1024) void k_scan(const int* __restrict__ deg,
    int* __restrict__ offs, int* __restrict__ cursor,
    float* __restrict__ lnum, float* __restrict__ lcnt, int* __restrict__ ticket)
{
  __shared__ int wsums[16];
  __shared__ int woffs[16];
  int tid = threadIdx.x, lane = tid & 63, wv = tid >> 6;
  if (tid < GG) { lnum[tid] = 0.0f; lcnt[tid] = 0.0f; }
  if (tid == 1022) *ticket = 0;
  int base = tid * 20;
  int loc[20];
  int s = 0;
#pragma unroll
  for (int j = 0; j < 20; ++j) {
    int idx = base + j;
    int v = (idx < NN) ? deg[idx] : 0;
    loc[j] = s; s += v;
  }
  int inc = s;
  for (int o = 1; o < 64; o <<= 1) {
    int v = __shfl_up(inc, o, 64);
    if (lane >= o) inc += v;
  }
  if (lane == 63) wsums[wv] = inc;
  __syncthreads();
  if (wv == 0 && lane < 16) {
    int v = wsums[lane];
    int i2 = v;
    for (int o = 1; o < 16; o <<= 1) {
      int vv = __shfl_up(i2, o, 16);
      if (lane >= o) i2 += vv;
    }
    woffs[lane] = i2 - v;
  }
  __syncthreads();
  int texcl = woffs[wv] + (inc - s);
#pragma unroll
  for (int j = 0; j < 20; ++j) {
    int idx = base + j;
    if (idx < NN) { int v = texcl + loc[j]; offs[idx] = v; cursor[idx] = v; }
  }
  if (tid == 1023) offs[NN] = EE;
}

// ---------------- K4: edge geometry, written into receiver-sorted slots ------
__global__ __launch_bounds__(256) void k_edge2(
    const float* __restrict__ pos_noisy, const float* __restrict__ shifts,
    const int* __restrict__ ei, int* __restrict__ cursor,
    ushort_t* __restrict__ Ys, ushort_t* __restrict__ efs, int* __restrict__ snds)
{
  int e = blockIdx.x * 256 + threadIdx.x;  // EE exact
  int snd = ei[e], rcv = ei[EE + e];
  float vx = pos_noisy[rcv * 3 + 0] - pos_noisy[snd * 3 + 0] + shifts[e * 3 + 0];
  float vy = pos_noisy[rcv * 3 + 1] - pos_noisy[snd * 3 + 1] + shifts[e * 3 + 1];
  float vz = pos_noisy[rcv * 3 + 2] - pos_noisy[snd * 3 + 2] + shifts[e * 3 + 2];
  float r2 = vx * vx + vy * vy + vz * vz + 1e-12f;
  float r = sqrtf(r2);
  float inv = 1.0f / r;
  float x = vx * inv, y = vy * inv, z = vz * inv;

  const float s3 = 1.7320508075688772f, s15 = 3.872983346207417f, s5 = 2.23606797749979f;
  const float s105 = 10.246950765959598f, s7 = 2.6457513110645907f;
  const float s35_8 = 2.091650066335189f, s21_8 = 1.6201851746019651f;
  float yv[16];
  yv[0] = 1.0f;
  yv[1] = s3 * x; yv[2] = s3 * y; yv[3] = s3 * z;
  yv[4] = s15 * x * y;
  yv[5] = s15 * y * z;
  yv[6] = 0.5f * s5 * (3.0f * z * z - 1.0f);
  yv[7] = s15 * x * z;
  yv[8] = 0.5f * s15 * (x * x - y * y);
  yv[9] = s35_8 * y * (3.0f * x * x - y * y);
  yv[10] = s105 * x * y * z;
  yv[11] = s21_8 * y * (5.0f * z * z - 1.0f);
  yv[12] = 0.5f * s7 * (5.0f * z * z * z - 3.0f * z);
  yv[13] = s21_8 * x * (5.0f * z * z - 1.0f);
  yv[14] = 0.5f * s105 * z * (x * x - y * y);
  yv[15] = s35_8 * x * (x * x - 3.0f * y * y);

  // radial embed: sqrt(2/5) * sin(n*pi*rc/5)/rc * poly_cutoff(r/5)
  float rc = fmaxf(r, 1e-9f);
  float pref = 0.6324555320336759f / rc;
  float th = 0.6283185307179586f * rc;
  float s1 = __sinf(th), c1 = __cosf(th);
  float xr = r * 0.2f;
  float fcut = 0.0f;
  if (xr < 1.0f) {
    float x2 = xr * xr, x3 = x2 * xr;
    float x6 = x3 * x3, x7 = x6 * xr, x8 = x7 * xr;
    fcut = 1.0f - 28.0f * x6 + 48.0f * x7 - 21.0f * x8;
  }
  float efv[8];
  float sp = 0.0f, scur = s1, c2 = 2.0f * c1;
#pragma unroll
  for (int b = 0; b < 8; ++b) {
    efv[b] = pref * scur * fcut;
    float nx = c2 * scur - sp;   // sin((n+1)th) = 2cos(th)sin(n th) - sin((n-1)th)
    sp = scur; scur = nx;
  }

  int slot = atomicAdd(&cursor[rcv], 1);
  snds[slot] = snd;
  uint4* Y4 = (uint4*)Ys;
  Y4[(size_t)slot * 2 + 0] = make_uint4(pk(yv[0], yv[1]), pk(yv[2], yv[3]),
                                        pk(yv[4], yv[5]), pk(yv[6], yv[7]));
  Y4[(size_t)slot * 2 + 1] = make_uint4(pk(yv[8], yv[9]), pk(yv[10], yv[11]),
                                        pk(yv[12], yv[13]), pk(yv[14], yv[15]));
  ((uint4*)efs)[slot] = make_uint4(pk(efv[0], efv[1]), pk(efv[2], efv[3]),
                                   pk(efv[4], efv[5]), pk(efv[6], efv[7]));
}

// ---------------- K5: fused layer v2 -----------------------------------------
// Wave = node. Per 16-edge tile: h1 in regs -> MFMA (W2^T frags in regs) ->
// ss epilogue -> ds_write bf16 tile -> round-7 streaming aggregation from LDS.
// LDS: [0,18432) w2t (reused after tiles: lagg 8192 + lf 2048);
//      [18432,20480) w1s f32; [20480,37376) rwt[4 waves][16][132] ushort.
__global__ __launch_bounds__(256) void k_flay(
    const ushort_t* __restrict__ efs, const ushort_t* __restrict__ Ys,
    const int* __restrict__ snds, const int* __restrict__ offs,
    const float* __restrict__ W_r1, const float* __restrict__ W_r2,
    const float* __restrict__ scal_in, float* __restrict__ scal_out,
    const float* __restrict__ W_mix, const float* __restrict__ W_prod,
    const float* __restrict__ W_ro_s, const float* __restrict__ W_ro_v,
    const float* __restrict__ sc_skip, float* __restrict__ pred, int layer)
{
  __shared__ __align__(16) char lds[37376];
  ushort_t (*w2t)[72] = (ushort_t(*)[72])lds;              // phase A
  float (*lagg)[CC][16] = (float(*)[CC][16])lds;           // phase C (aliases w2t)
  float (*lf)[CC][4] = (float(*)[CC][4])(lds + 8192);      // phase C
  float* w1s = (float*)(lds + 18432);                      // persistent

  int tid = threadIdx.x;
  int w = tid >> 6, lane = tid & 63;
  ushort_t (*rwt)[132] = (ushort_t(*)[132])(lds + 20480 + w * 4224);

  int n0 = blockIdx.x * NPB;
  const float* W1g = W_r1 + layer * NBB * HIDD;
  const float* W2g = W_r2 + layer * HIDD * 128;

  for (int idx = tid; idx < HIDD * 128; idx += 256) {
    int k = idx >> 7, n = idx & 127;
    w2t[n][k] = f2b(W2g[idx]);
  }
  for (int idx = tid; idx < NBB * HIDD; idx += 256) w1s[idx] = W1g[idx];
  __syncthreads();

  int c16 = lane & 15, quad = lane >> 4;
  bf16x8 bfr[16];
#pragma unroll
  for (int nt = 0; nt < 8; ++nt)
#pragma unroll
    for (int kt = 0; kt < 2; ++kt)
      bfr[nt * 2 + kt] = *(const bf16x8*)&w2t[nt * 16 + c16][kt * 32 + quad * 8];

  int oj = offs[n0 + w];
  int dj = min(offs[n0 + w + 1] - oj, MAXDEG);

  int cA = lane >> 1, kh = lane & 1, kb = kh * 8;
  float acc0 = 0, acc1 = 0, acc2 = 0, acc3 = 0, acc4 = 0, acc5 = 0, acc6 = 0, acc7 = 0;
  const uint4* Y4 = (const uint4*)Ys;

  for (int kbase = 0; kbase < dj; kbase += 16) {
    // ---- h1 A-fragments in registers (lane covers edge kbase+c16, k=quad*8..)
    bf16x8 a0, a1;
    {
      int kc = kbase + c16;
      float ef8[8] = {0, 0, 0, 0, 0, 0, 0, 0};
      if (kc < dj) {
        uint4 q = ((const uint4*)efs)[(size_t)(oj + kc)];
        ef8[0] = lo16(q.x); ef8[1] = hi16(q.x); ef8[2] = lo16(q.y); ef8[3] = hi16(q.y);
        ef8[4] = lo16(q.z); ef8[5] = hi16(q.z); ef8[6] = lo16(q.w); ef8[7] = hi16(q.w);
      }
      float h0[8] = {0, 0, 0, 0, 0, 0, 0, 0};
      float h1v[8] = {0, 0, 0, 0, 0, 0, 0, 0};
#pragma unroll
      for (int b = 0; b < 8; ++b) {
        const float* wb = &w1s[b * HIDD];
        float4 wa = *(const float4*)&wb[quad * 8];
        float4 wbv = *(const float4*)&wb[quad * 8 + 4];
        float4 wc = *(const float4*)&wb[32 + quad * 8];
        float4 wd = *(const float4*)&wb[32 + quad * 8 + 4];
        float e = ef8[b];
        h0[0] = fmaf(e, wa.x, h0[0]); h0[1] = fmaf(e, wa.y, h0[1]);
        h0[2] = fmaf(e, wa.z, h0[2]); h0[3] = fmaf(e, wa.w, h0[3]);
        h0[4] = fmaf(e, wbv.x, h0[4]); h0[5] = fmaf(e, wbv.y, h0[5]);
        h0[6] = fmaf(e, wbv.z, h0[6]); h0[7] = fmaf(e, wbv.w, h0[7]);
        h1v[0] = fmaf(e, wc.x, h1v[0]); h1v[1] = fmaf(e, wc.y, h1v[1]);
        h1v[2] = fmaf(e, wc.z, h1v[2]); h1v[3] = fmaf(e, wc.w, h1v[3]);
        h1v[4] = fmaf(e, wd.x, h1v[4]); h1v[5] = fmaf(e, wd.y, h1v[5]);
        h1v[6] = fmaf(e, wd.z, h1v[6]); h1v[7] = fmaf(e, wd.w, h1v[7]);
      }
#pragma unroll
      for (int jj = 0; jj < 8; ++jj) {
        float v0 = h0[jj];  v0 = v0 / (1.0f + __expf(-v0));
        float v1 = h1v[jj]; v1 = v1 / (1.0f + __expf(-v1));
        a0[jj] = (short)f2b(v0);
        a1[jj] = (short)f2b(v1);
      }
    }
    // ---- senders for this lane's 4 D-rows (clamped to valid memory)
    int snd_[4];
#pragma unroll
    for (int r = 0; r < 4; ++r) {
      int kr = kbase + quad * 4 + r;
      snd_[r] = snds[oj + ((kr < dj) ? kr : (dj - 1))];
    }
    // ---- MFMA + ss epilogue -> LDS tile (row stride 132 -> 2-way max conflicts)
#pragma unroll
    for (int nt = 0; nt < 8; ++nt) {
      f32x4 acc = {0.0f, 0.0f, 0.0f, 0.0f};
      acc = __builtin_amdgcn_mfma_f32_16x16x32_bf16(a0, bfr[nt * 2 + 0], acc, 0, 0, 0);
      acc = __builtin_amdgcn_mfma_f32_16x16x32_bf16(a1, bfr[nt * 2 + 1], acc, 0, 0, 0);
      int cc = 4 * nt + (c16 >> 2);
#pragma unroll
      for (int r = 0; r < 4; ++r)
        rwt[quad * 4 + r][nt * 16 + c16] = f2b(acc[r] * scal_in[(size_t)snd_[r] * CC + cc]);
    }
    asm volatile("s_waitcnt lgkmcnt(0)" ::: "memory");   // same-wave write->read
    // ---- round-7 streaming aggregation, rw from LDS
    int emax = min(16, dj - kbase);
    for (int e = 0; e < emax; ++e) {
      size_t ge = (size_t)(oj + kbase + e);
      uint4 q = Y4[ge * 2 + kh];
      uint2 rp = *(const uint2*)&rwt[e][cA * 4];
      float r0 = lo16(rp.x), r1 = hi16(rp.x), r2v = lo16(rp.y), r3 = hi16(rp.y);
      // L_OF_LM: kh0 -> l={0,1,1,1,2,2,2,2}; kh1 -> l={2,3,3,3,3,3,3,3}
      float w0 = kh ? r2v : r0, w13 = kh ? r3 : r1, w47 = kh ? r3 : r2v;
      acc0 = fmaf(w0,  lo16(q.x), acc0);
      acc1 = fmaf(w13, hi16(q.x), acc1);
      acc2 = fmaf(w13, lo16(q.y), acc2);
      acc3 = fmaf(w13, hi16(q.y), acc3);
      acc4 = fmaf(w47, lo16(q.z), acc4);
      acc5 = fmaf(w47, hi16(q.z), acc5);
      acc6 = fmaf(w47, lo16(q.w), acc6);
      acc7 = fmaf(w47, hi16(q.w), acc7);
    }
  }
  __syncthreads();   // all waves done with w2t/bfr region -> reuse for lagg/lf

  const float invavg = 1.0f / 16.0f;
  lagg[w][cA][kb + 0] = acc0 * invavg;
  lagg[w][cA][kb + 1] = acc1 * invavg;
  lagg[w][cA][kb + 2] = acc2 * invavg;
  lagg[w][cA][kb + 3] = acc3 * invavg;
  lagg[w][cA][kb + 4] = acc4 * invavg;
  lagg[w][cA][kb + 5] = acc5 * invavg;
  lagg[w][cA][kb + 6] = acc6 * invavg;
  lagg[w][cA][kb + 7] = acc7 * invavg;
  __syncthreads();

  // ---- mix + poly + skip + scal_out + lf (round-7 verbatim)
  int d = cA;
  int n = n0 + w;
  float ft[8] = {0, 0, 0, 0, 0, 0, 0, 0};
  const float* Wm = W_mix + layer * 4096;
  for (int cc2 = 0; cc2 < CC; ++cc2) {
    float m0 = Wm[cc2 * CC + d];
    float m1 = Wm[1024 + cc2 * CC + d];
    float m2 = Wm[2048 + cc2 * CC + d];
    float m3 = Wm[3072 + cc2 * CC + d];
    float u0 = kh ? m2 : m0;
    float u13 = kh ? m3 : m1;
    float u47 = kh ? m3 : m2;
    ft[0] = fmaf(lagg[w][cc2][kb + 0], u0, ft[0]);
    ft[1] = fmaf(lagg[w][cc2][kb + 1], u13, ft[1]);
    ft[2] = fmaf(lagg[w][cc2][kb + 2], u13, ft[2]);
    ft[3] = fmaf(lagg[w][cc2][kb + 3], u13, ft[3]);
    ft[4] = fmaf(lagg[w][cc2][kb + 4], u47, ft[4]);
    ft[5] = fmaf(lagg[w][cc2][kb + 5], u47, ft[5]);
    ft[6] = fmaf(lagg[w][cc2][kb + 6], u47, ft[6]);
    ft[7] = fmaf(lagg[w][cc2][kb + 7], u47, ft[7]);
  }
  float sv = __shfl(ft[0], lane & 62, 64);   // k=0 pre-poly from even lane of pair
  const float* Wp = W_prod + layer * 96;
  float p0 = Wp[d], p1 = Wp[32 + d], p2 = Wp[64 + d];
  float poly = fmaf(fmaf(p2, sv, p1), sv, p0);
#pragma unroll
  for (int j = 0; j < 8; ++j) ft[j] *= poly;
  if (layer == 0 && kh == 0) ft[0] += sc_skip[n * CC + d];
  if (kh == 0) {
    scal_out[n * CC + d] = ft[0];
    lf[w][d][0] = ft[0]; lf[w][d][1] = ft[1]; lf[w][d][2] = ft[2]; lf[w][d][3] = ft[3];
  }
  __syncthreads();
  if (lane < 13) {
    float sum = 0.0f;
    if (lane < 10) {
      const float* Wr = W_ro_s + layer * CC * NEL;
      for (int dd = 0; dd < CC; ++dd) sum = fmaf(lf[w][dd][0], Wr[dd * NEL + lane], sum);
    } else {
      int mm = lane - 10;
      const float* Wv = W_ro_v + layer * CC;
      for (int dd = 0; dd < CC; ++dd) sum = fmaf(lf[w][dd][1 + mm], Wv[dd], sum);
    }
    pred[n * 13 + lane] += sum;
  }
}

// ---------------- K7: loss accumulation + final (last-block ticket) ----------
__global__ __launch_bounds__(256) void k_loss(const float* __restrict__ pred,
    const float* __restrict__ eps, const int* __restrict__ batch,
    float* __restrict__ lnum, float* __restrict__ lcnt,
    int* __restrict__ ticket, float* __restrict__ out, int nblocks)
{
  __shared__ float psum[GG];
  __shared__ int pcnt[GG];
  __shared__ int lastflag;
  int tid = threadIdx.x;
  if (tid < GG) { psum[tid] = 0.0f; pcnt[tid] = 0; }
  __syncthreads();
  int n = blockIdx.x * 256 + tid;
  if (n < NN) {
    int g = batch[n];
    float sum = 0.0f;
#pragma unroll
    for (int j = 0; j < 13; ++j) {
      float dlt = pred[n * 13 + j] - eps[n * 13 + j];
      sum = fmaf(dlt, dlt, sum);
    }
    atomicAdd(&psum[g], sum);
    atomicAdd(&pcnt[g], 1);
  }
  __syncthreads();
  if (tid < GG && pcnt[tid] > 0) {
    atomicAdd(&lnum[tid], psum[tid]);
    atomicAdd(&lcnt[tid], (float)pcnt[tid]);
  }
  __syncthreads();
  if (tid == 0) {
    __threadfence();
    int t = atomicAdd(ticket, 1);
    lastflag = (t == nblocks - 1) ? 1 : 0;
  }
  __syncthreads();
  if (lastflag && tid < GG) {
    float num = atomicAdd(&lnum[tid], 0.0f);   // device-coherent read
    float cnt = atomicAdd(&lcnt[tid], 0.0f);
    out[tid] = 0.5f * num / (fmaxf(cnt, 1.0f) * 13.0f);
  }
}

extern "C" void kernel_launch(void* const* d_in, const int* in_sizes, int n_in,
                              void* d_out, int out_size, void* d_ws, size_t ws_size,
                              hipStream_t stream) {
  const float* positions  = (const float*)d_in[0];
  const float* node_attrs = (const float*)d_in[1];
  const float* shifts     = (const float*)d_in[2];
  const float* eps        = (const float*)d_in[3];
  const float* alpha_bar  = (const float*)d_in[4];
  const float* W_embed    = (const float*)d_in[5];
  const float* W_r1       = (const float*)d_in[6];
  const float* W_r2       = (const float*)d_in[7];
  const float* W_mix      = (const float*)d_in[8];
  const float* W_sc       = (const float*)d_in[9];
  const float* W_prod     = (const float*)d_in[10];
  const float* W_ro_s     = (const float*)d_in[11];
  const float* W_ro_v     = (const float*)d_in[12];
  const int* edge_index   = (const int*)d_in[13];
  const int* batch        = (const int*)d_in[14];
  const int* tarr         = (const int*)d_in[15];
  float* out = (float*)d_out;

  char* ws = (char*)d_ws;
  size_t off = 0;
  auto alloc = [&](size_t bytes) -> void* {
    void* p = ws + off;
    off = (off + bytes + 255) & ~(size_t)255;
    return p;
  };
  // total ~25 MB
  float* pos_noisy = (float*)alloc(NN * 3 * 4);
  float* scalA     = (float*)alloc(NN * CC * 4);
  float* scalB     = (float*)alloc(NN * CC * 4);
  float* sc_skip   = (float*)alloc(NN * CC * 4);
  float* pred      = (float*)alloc(NN * 13 * 4);
  ushort_t* Ys     = (ushort_t*)alloc((size_t)EE * 16 * 2);  // sorted, bf16
  ushort_t* efs    = (ushort_t*)alloc((size_t)EE * 8 * 2);   // sorted, bf16
  int* snds        = (int*)alloc((size_t)EE * 4);            // sorted sender ids
  int* deg         = (int*)alloc(NN * 4);
  int* offs        = (int*)alloc((NN + 1) * 4);
  int* cursor      = (int*)alloc(NN * 4);
  float* lnum      = (float*)alloc(GG * 4);
  float* lcnt      = (float*)alloc(GG * 4);
  int* ticket      = (int*)alloc(4);
  (void)ws_size; (void)in_sizes; (void)n_in; (void)out_size;

  const int NB_N = (NN + 255) / 256;   // 79
  const int NB_E = EE / 256;           // 1250

  k_prep<<<NB_N, 256, 0, stream>>>(positions, node_attrs, eps, alpha_bar, W_embed,
                                   W_sc, batch, tarr, pos_noisy, scalA, sc_skip, pred, deg);
  k_edge_deg<<<NB_E, 256, 0, stream>>>(edge_index, deg);
  k_scan<<<1, 1024, 0, stream>>>(deg, offs, cursor, lnum, lcnt, ticket);
  k_edge2<<<NB_E, 256, 0, stream>>>(pos_noisy, shifts, edge_index, cursor, Ys, efs, snds);

  for (int layer = 0; layer < 2; ++layer) {
    const float* sin_p = (layer == 0) ? scalA : scalB;
    float* sout_p      = (layer == 0) ? scalB : scalA;
    k_flay<<<NN / NPB, 256, 0, stream>>>(efs, Ys, snds, offs, W_r1, W_r2,
                                         sin_p, sout_p, W_mix, W_prod,
                                         W_ro_s, W_ro_v, sc_skip, pred, layer);
  }

  k_loss<<<NB_N, 256, 0, stream>>>(pred, eps, batch, lnum, lcnt, ticket, out, NB_N);
}